// Round 9
// baseline (314.267 us; speedup 1.0000x reference)
//
#include <hip/hip_runtime.h>
#include <hip/hip_bf16.h>

#define B_  8
#define LQ  160
#define LK  160

// ---------------------------------------------------------------------------
// Multi-op fp32 GEMM, 32x64 tile (higher occupancy: 320 blocks/op), full K,
// software-pipelined global loads. C[m,n] = sum_k A[m,k]*W[n,k] + bias[n].
// A [1280,512] lda=512, W [N,K], C ld 512. 256 threads, 2x4 micro.
// As padded [16][33] -> conflict-free transpose staging.
// ---------------------------------------------------------------------------
struct GOps {
    const float* A[3];
    const float* W[3];
    const float* Bi[3];
    float*       C[3];
};

__global__ __launch_bounds__(256) void gemm_f(GOps ops, int K)
{
    const int op = blockIdx.z;
    const float* __restrict__ A  = ops.A[op];
    const float* __restrict__ W  = ops.W[op];
    const float* __restrict__ Bi = ops.Bi[op];
    float* __restrict__       C  = ops.C[op];

    const int m0 = blockIdx.y << 5;
    const int n0 = blockIdx.x << 6;
    const int tid = threadIdx.x;
    const int tm  = tid >> 4;          // 0..15 -> rows tm*2+{0,1}
    const int tn  = tid & 15;          // cols tn*4
    const int lr  = tid >> 2;          // W load row 0..63
    const int lk4 = (tid & 3) << 2;    // W load k
    const int ar  = tid >> 2;          // A load row 0..31 (tid<128)
    const int ak4 = (tid & 3) << 2;    // A load k

    __shared__ float As[16][33];
    __shared__ float Ws[16][64];

    float acc[2][4];
#pragma unroll
    for (int i = 0; i < 2; i++)
#pragma unroll
        for (int j = 0; j < 4; j++) acc[i][j] = 0.f;

    const float* Arow = A + (long)(m0 + ar) * 512 + ak4;
    const float* Wrow = W + (long)(n0 + lr) * K + lk4;
    float4 av, wv;
    if (tid < 128) av = *(const float4*)(Arow);
    wv = *(const float4*)(Wrow);

    for (int k0 = 0; k0 < K; k0 += 16) {
        __syncthreads();
        if (tid < 128) {
            As[ak4 + 0][ar] = av.x; As[ak4 + 1][ar] = av.y;
            As[ak4 + 2][ar] = av.z; As[ak4 + 3][ar] = av.w;
        }
        Ws[lk4 + 0][lr] = wv.x; Ws[lk4 + 1][lr] = wv.y;
        Ws[lk4 + 2][lr] = wv.z; Ws[lk4 + 3][lr] = wv.w;
        __syncthreads();
        if (k0 + 16 < K) {
            if (tid < 128) av = *(const float4*)(Arow + k0 + 16);
            wv = *(const float4*)(Wrow + k0 + 16);
        }
#pragma unroll
        for (int kk = 0; kk < 16; kk++) {
            const float a0 = As[kk][(tm << 1) + 0];
            const float a1 = As[kk][(tm << 1) + 1];
            const float4 b4 = *(const float4*)(&Ws[kk][tn << 2]);
            const float bb[4] = {b4.x, b4.y, b4.z, b4.w};
#pragma unroll
            for (int j = 0; j < 4; j++) {
                acc[0][j] = fmaf(a0, bb[j], acc[0][j]);
                acc[1][j] = fmaf(a1, bb[j], acc[1][j]);
            }
        }
    }

    const float4 bv = *(const float4*)(Bi + n0 + (tn << 2));
    const float bArr[4] = {bv.x, bv.y, bv.z, bv.w};

#pragma unroll
    for (int i = 0; i < 2; i++) {
        float4 vo;
        vo.x = acc[i][0] + bArr[0]; vo.y = acc[i][1] + bArr[1];
        vo.z = acc[i][2] + bArr[2]; vo.w = acc[i][3] + bArr[3];
        *(float4*)(C + (long)(m0 + (tm << 1) + i) * 512 + n0 + (tn << 2)) = vo;
    }
}

// ---------------------------------------------------------------------------
// Fused per-chunk merge projections (K=64 GEMMs). z<8 -> y0 chunk z, else y1.
// BOTH paths use remapped columns: block covers s in [s0,s0+8) x r in [0,8),
// logical col ln -> weight row t = (ln&7)*64 + s0 + (ln>>3).
// y0: LDS-transposed to [s8][k8][r], written as contiguous 512-float runs/s
//     into y0t[b][c][s][k][r].
// y1: LDS-transposed to [m8][s8*8+r], written as contiguous 64-float runs/m
//     into y1p[m][c][s][r]  (c*512 + s*8 + r) -- r innermost.
// ---------------------------------------------------------------------------
__global__ __launch_bounds__(256) void y_proj(
    const float* __restrict__ x0, const float* __restrict__ wm0, const float* __restrict__ bm0,
    const float* __restrict__ x1, const float* __restrict__ wm1, const float* __restrict__ bm1,
    float* __restrict__ y0t, float* __restrict__ y1p)
{
    const int z   = blockIdx.z;
    const bool is1 = z >= 8;
    const int c   = is1 ? z - 8 : z;
    const float* A  = (is1 ? x1 : x0) + (c << 6);      // column slice, lda=512
    const float* W  = (is1 ? wm1 : wm0) + c * 32768;   // [512][64]
    const float* Bi = (is1 ? bm1 : bm0) + (c << 9);

    const int m0 = blockIdx.y << 6;
    const int s0 = blockIdx.x << 3;
    const int tid = threadIdx.x;
    const int tm  = tid >> 4;
    const int tn  = tid & 15;
    const int lr  = tid >> 2;
    const int lk4 = (tid & 3) << 2;

    __shared__ float As[16][64];
    __shared__ float Ws[16][64];
    __shared__ float outT[4096];

    float acc[4][4];
#pragma unroll
    for (int i = 0; i < 4; i++)
#pragma unroll
        for (int j = 0; j < 4; j++) acc[i][j] = 0.f;

    const int wrow = ((lr & 7) << 6) + s0 + (lr >> 3);
    const float* Arow = A + (long)(m0 + lr) * 512 + lk4;
    const float* Wrow = W + (long)wrow * 64 + lk4;
    float4 av = *(const float4*)(Arow);
    float4 wv = *(const float4*)(Wrow);

    for (int k0 = 0; k0 < 64; k0 += 16) {
        __syncthreads();
        As[lk4 + 0][lr] = av.x; As[lk4 + 1][lr] = av.y;
        As[lk4 + 2][lr] = av.z; As[lk4 + 3][lr] = av.w;
        Ws[lk4 + 0][lr] = wv.x; Ws[lk4 + 1][lr] = wv.y;
        Ws[lk4 + 2][lr] = wv.z; Ws[lk4 + 3][lr] = wv.w;
        __syncthreads();
        if (k0 + 16 < 64) {
            av = *(const float4*)(Arow + k0 + 16);
            wv = *(const float4*)(Wrow + k0 + 16);
        }
#pragma unroll
        for (int kk = 0; kk < 16; kk++) {
            const float4 a4 = *(const float4*)(&As[kk][tm << 2]);
            const float4 b4 = *(const float4*)(&Ws[kk][tn << 2]);
            const float aa[4] = {a4.x, a4.y, a4.z, a4.w};
            const float bb[4] = {b4.x, b4.y, b4.z, b4.w};
#pragma unroll
            for (int i = 0; i < 4; i++)
#pragma unroll
                for (int j = 0; j < 4; j++)
                    acc[i][j] = fmaf(aa[i], bb[j], acc[i][j]);
        }
    }

    // bias for logical column ln = tn*4+j: t = (ln&7)*64 + s0 + (ln>>3)
    float bArr[4];
#pragma unroll
    for (int j = 0; j < 4; j++) {
        const int ln = (tn << 2) + j;
        bArr[j] = Bi[((ln & 7) << 6) + s0 + (ln >> 3)];
    }
    __syncthreads();
    if (is1) {
        // stage [m8][s8*8 + r]
#pragma unroll
        for (int i = 0; i < 4; i++) {
            const int m8 = (tm << 2) + i;
#pragma unroll
            for (int j = 0; j < 4; j++) {
                const int ln = (tn << 2) + j;
                outT[(m8 << 6) + ((ln >> 3) << 3) + (ln & 7)] = acc[i][j] + bArr[j];
            }
        }
        __syncthreads();
        // write: 64 rows x 64 contiguous floats at y1p[m][c*512 + s0*8]
#pragma unroll
        for (int p = 0; p < 4; p++) {
            const int idx = tid + (p << 8);     // float4 id 0..1023
            const int m8  = idx >> 4;
            const int f4  = idx & 15;
            *(float4*)(y1p + (long)(m0 + m8) * 4096 + (c << 9) + (s0 << 3) + (f4 << 2))
                = *(const float4*)&outT[idx << 2];
        }
    } else {
        // stage [s8][k8][r]
#pragma unroll
        for (int i = 0; i < 4; i++) {
            const int k8 = (tm << 2) + i;
#pragma unroll
            for (int j = 0; j < 4; j++) {
                const int ln = (tn << 2) + j;
                outT[((ln >> 3) << 9) + (k8 << 3) + (ln & 7)] = acc[i][j] + bArr[j];
            }
        }
        __syncthreads();
        // write 8 runs of 512 contiguous floats (one per s8)
#pragma unroll
        for (int p = 0; p < 4; p++) {
            const int s8  = (p << 1) + (tid >> 7);
            const int u4  = tid & 127;
            const int k8  = u4 >> 1;
            const int r   = (u4 & 1) << 2;
            const int m   = m0 + k8;
            const int bidx = m / 160;
            const int kmod = m - bidx * 160;
            const int s   = s0 + s8;
            float4* dst = (float4*)(y0t +
                (((long)(bidx * 8 + c) * 64 + s) * 160 + kmod) * 8 + r);
            *dst = *(const float4*)&outT[(s8 << 9) + (u4 << 2)];
        }
    }
}

// ---------------------------------------------------------------------------
// Per-(b, 4-q-tile, c) partial scores. y1 AND w_bo staged in LDS in the SAME
// order as y1p (straight float4 copy -> zero conflicts, zero transpose); loop
// reads are same-address broadcasts (ds_read_b128, in-order lgkmcnt -> the
// compiler can pipeline, unlike the out-of-order s_load path of r8).
// No SMEM in the hot loop. y0: per-lane 2x float4 per s, prefetched 1 ahead.
// scores_p: [B][LQ][C][LK]
// ---------------------------------------------------------------------------
__global__ __launch_bounds__(192) void score_partial(
    const float* __restrict__ y1p, const float* __restrict__ y0t,
    const float* __restrict__ wbo, float* __restrict__ scores_p)
{
    const int id = blockIdx.x;
    const int c  = id & 7;
    const int j  = id >> 3;
    const int b  = j / 40;
    const int q0 = (j - b * 40) << 2;
    const int tid = threadIdx.x;
    const int k  = tid;
    const int kc = k < LK ? k : (LK - 1);     // clamp redundant lanes

    __shared__ float y1c[4][512];   // [q][s*8+r] == y1p order
    __shared__ float wbs[64];

    {
        const float4* src = (const float4*)(y1p + (long)(b * LQ + q0) * 4096 + (c << 9));
        float4* dst = (float4*)&y1c[0][0];
        for (int t = tid; t < 512; t += 192) {
            const int qq = t >> 7, e = t & 127;
            dst[t] = src[qq * 1024 + e];      // q-row stride 4096 floats = 1024 f4
        }
        if (tid < 16) ((float4*)wbs)[tid] = ((const float4*)(wbo + (c << 6)))[tid];
    }
    __syncthreads();

    const float* y1r0 = &y1c[0][0];
    const float* y1r1 = &y1c[1][0];
    const float* y1r2 = &y1c[2][0];
    const float* y1r3 = &y1c[3][0];
    const float* ybc = y0t + (((long)(b * 8 + c) * 64) * 160 + kc) * 8;

    float num[4] = {0.f, 0.f, 0.f, 0.f};
    float den[4] = {0.f, 0.f, 0.f, 0.f};

    float4 a0 = *(const float4*)(ybc);
    float4 a1 = *(const float4*)(ybc + 4);
#pragma unroll 2
    for (int s = 0; s < 64; s++) {
        const float a[8] = {a0.x, a0.y, a0.z, a0.w, a1.x, a1.y, a1.z, a1.w};
        const int sn = (s + 1) & 63;          // last iter reloads s=0 (harmless)
        a0 = *(const float4*)(ybc + (long)sn * 1280);
        a1 = *(const float4*)(ybc + (long)sn * 1280 + 4);
        const float w = wbs[s];
        const int o = s << 3;
        {
            float zv = a[0] * y1r0[o];
            zv = fmaf(a[1], y1r0[o+1], zv); zv = fmaf(a[2], y1r0[o+2], zv);
            zv = fmaf(a[3], y1r0[o+3], zv); zv = fmaf(a[4], y1r0[o+4], zv);
            zv = fmaf(a[5], y1r0[o+5], zv); zv = fmaf(a[6], y1r0[o+6], zv);
            zv = fmaf(a[7], y1r0[o+7], zv);
            const float az = fabsf(zv);
            num[0] = fmaf(copysignf(__builtin_amdgcn_sqrtf(az), zv), w, num[0]);
            den[0] += az;
        }
        {
            float zv = a[0] * y1r1[o];
            zv = fmaf(a[1], y1r1[o+1], zv); zv = fmaf(a[2], y1r1[o+2], zv);
            zv = fmaf(a[3], y1r1[o+3], zv); zv = fmaf(a[4], y1r1[o+4], zv);
            zv = fmaf(a[5], y1r1[o+5], zv); zv = fmaf(a[6], y1r1[o+6], zv);
            zv = fmaf(a[7], y1r1[o+7], zv);
            const float az = fabsf(zv);
            num[1] = fmaf(copysignf(__builtin_amdgcn_sqrtf(az), zv), w, num[1]);
            den[1] += az;
        }
        {
            float zv = a[0] * y1r2[o];
            zv = fmaf(a[1], y1r2[o+1], zv); zv = fmaf(a[2], y1r2[o+2], zv);
            zv = fmaf(a[3], y1r2[o+3], zv); zv = fmaf(a[4], y1r2[o+4], zv);
            zv = fmaf(a[5], y1r2[o+5], zv); zv = fmaf(a[6], y1r2[o+6], zv);
            zv = fmaf(a[7], y1r2[o+7], zv);
            const float az = fabsf(zv);
            num[2] = fmaf(copysignf(__builtin_amdgcn_sqrtf(az), zv), w, num[2]);
            den[2] += az;
        }
        {
            float zv = a[0] * y1r3[o];
            zv = fmaf(a[1], y1r3[o+1], zv); zv = fmaf(a[2], y1r3[o+2], zv);
            zv = fmaf(a[3], y1r3[o+3], zv); zv = fmaf(a[4], y1r3[o+4], zv);
            zv = fmaf(a[5], y1r3[o+5], zv); zv = fmaf(a[6], y1r3[o+6], zv);
            zv = fmaf(a[7], y1r3[o+7], zv);
            const float az = fabsf(zv);
            num[3] = fmaf(copysignf(__builtin_amdgcn_sqrtf(az), zv), w, num[3]);
            den[3] += az;
        }
    }
    if (k < LK) {
#pragma unroll
        for (int q = 0; q < 4; q++)
            scores_p[(((long)(b * LQ + q0 + q)) * 8 + c) * 160 + k] =
                num[q] / fmaxf(__builtin_amdgcn_sqrtf(den[q]), 1e-12f);
    }
}

// ---------------------------------------------------------------------------
// Sum partials over c, softmax over k, att@vv, write attedT [B][512][LQ].
// b_bo dropped: softmax is shift-invariant.
// ---------------------------------------------------------------------------
__global__ __launch_bounds__(256) void softmax_attv(
    const float* __restrict__ scores_p, const float* __restrict__ vv,
    float* __restrict__ attedT)
{
    const int b  = blockIdx.y;
    const int q0 = blockIdx.x << 2;
    const int tid = threadIdx.x;

    __shared__ float scs[4][160];
    __shared__ float invd[4];

    for (int t = tid; t < 640; t += 256) {
        const int q = t / 160;
        const int k = t - q * 160;
        const float* sp = scores_p + ((long)(b * LQ + q0 + q)) * 1280 + k;
        float s = 0.f;
#pragma unroll
        for (int c = 0; c < 8; c++) s += sp[c * 160];
        scs[q][k] = s;
    }
    __syncthreads();

    const int w    = tid >> 6;
    const int lane = tid & 63;
    {
        const int q = w;
        float m = -1e30f;
        for (int kk = lane; kk < LK; kk += 64) m = fmaxf(m, scs[q][kk]);
#pragma unroll
        for (int off = 32; off; off >>= 1) m = fmaxf(m, __shfl_xor(m, off, 64));
        float sum = 0.f;
        for (int kk = lane; kk < LK; kk += 64) {
            const float e = __expf(scs[q][kk] - m);
            scs[q][kk] = e;
            sum += e;
        }
#pragma unroll
        for (int off = 32; off; off >>= 1) sum += __shfl_xor(sum, off, 64);
        if (lane == 0) invd[q] = 1.f / sum;
    }
    __syncthreads();

    float acc[2][4] = {{0.f,0.f,0.f,0.f},{0.f,0.f,0.f,0.f}};
    const float* vb = vv + (long)b * (LK * 512);
    for (int kk = 0; kk < LK; kk++) {
        const float* vr = vb + kk * 512;
        const float p0 = scs[0][kk], p1 = scs[1][kk];
        const float p2 = scs[2][kk], p3 = scs[3][kk];
        const float v0 = vr[tid], v1 = vr[tid + 256];
        acc[0][0] = fmaf(p0, v0, acc[0][0]); acc[0][1] = fmaf(p1, v0, acc[0][1]);
        acc[0][2] = fmaf(p2, v0, acc[0][2]); acc[0][3] = fmaf(p3, v0, acc[0][3]);
        acc[1][0] = fmaf(p0, v1, acc[1][0]); acc[1][1] = fmaf(p1, v1, acc[1][1]);
        acc[1][2] = fmaf(p2, v1, acc[1][2]); acc[1][3] = fmaf(p3, v1, acc[1][3]);
    }
#pragma unroll
    for (int j = 0; j < 2; j++) {
        const int h = tid + (j << 8);
#pragma unroll
        for (int q = 0; q < 4; q++)
            attedT[((long)b * 512 + h) * 160 + q0 + q] = acc[j][q] * invd[q];
    }
}

// ---------------------------------------------------------------------------
extern "C" void kernel_launch(void* const* d_in, const int* in_sizes, int n_in,
                              void* d_out, int out_size, void* d_ws, size_t ws_size,
                              hipStream_t stream) {
    const float* v    = (const float*)d_in[0];
    const float* kin  = (const float*)d_in[1];
    const float* q    = (const float*)d_in[2];
    const float* w_v  = (const float*)d_in[3];
    const float* b_v  = (const float*)d_in[4];
    const float* w_k  = (const float*)d_in[5];
    const float* b_k  = (const float*)d_in[6];
    const float* w_q  = (const float*)d_in[7];
    const float* b_q  = (const float*)d_in[8];
    const float* w0   = (const float*)d_in[9];
    const float* b0   = (const float*)d_in[10];
    const float* w1   = (const float*)d_in[11];
    const float* b1   = (const float*)d_in[12];
    const float* wm0  = (const float*)d_in[13];
    const float* bm0  = (const float*)d_in[14];
    const float* wm1  = (const float*)d_in[15];
    const float* bm1  = (const float*)d_in[16];
    const float* w_bo = (const float*)d_in[17];
    (void)d_in[18];  // b_bo unused: softmax is shift-invariant
    const float* w_m  = (const float*)d_in[19];
    const float* b_m  = (const float*)d_in[20];

    float* ws       = (float*)d_ws;
    float* vv       = ws;                  // 655360
    float* kk       = ws + 655360;         // 655360
    float* qq       = ws + 1310720;        // 655360
    float* x0       = ws + 1966080;        // 655360
    float* x1       = ws + 2621440;        // 655360
    float* y1p      = ws + 3276800;        // 5242880  [m][c][s][r]
    float* y0t      = ws + 8519680;        // 5242880  [B][c][s][k][r]
    float* attedT   = ws + 13762560;       // 655360   [B][512][LQ]
    float* scores_p = ws + 655360;         // 1638400, aliases kk/qq/x0 (dead by then)

    GOps oA;
    oA.A[0] = v;   oA.W[0] = w_v; oA.Bi[0] = b_v; oA.C[0] = vv;
    oA.A[1] = kin; oA.W[1] = w_k; oA.Bi[1] = b_k; oA.C[1] = kk;
    oA.A[2] = q;   oA.W[2] = w_q; oA.Bi[2] = b_q; oA.C[2] = qq;
    hipLaunchKernelGGL(gemm_f, dim3(8, 40, 3), dim3(256), 0, stream, oA, 512);

    GOps oB;
    oB.A[0] = kk; oB.W[0] = w0; oB.Bi[0] = b0; oB.C[0] = x0;
    oB.A[1] = qq; oB.W[1] = w1; oB.Bi[1] = b1; oB.C[1] = x1;
    oB.A[2] = nullptr; oB.W[2] = nullptr; oB.Bi[2] = nullptr; oB.C[2] = nullptr;
    hipLaunchKernelGGL(gemm_f, dim3(8, 40, 2), dim3(256), 0, stream, oB, 512);

    hipLaunchKernelGGL(y_proj, dim3(8, 20, 16), dim3(256), 0, stream,
                       x0, wm0, bm0, x1, wm1, bm1, y0t, y1p);

    hipLaunchKernelGGL(score_partial, dim3(2560), dim3(192), 0, stream,
                       y1p, y0t, w_bo, scores_p);

    hipLaunchKernelGGL(softmax_attv, dim3(40, 8), dim3(256), 0, stream,
                       scores_p, vv, attedT);

    GOps oF;
    oF.A[0] = attedT; oF.W[0] = w_m; oF.Bi[0] = b_m; oF.C[0] = (float*)d_out;
    oF.A[1] = nullptr; oF.W[1] = nullptr; oF.Bi[1] = nullptr; oF.C[1] = nullptr;
    oF.A[2] = nullptr; oF.W[2] = nullptr; oF.Bi[2] = nullptr; oF.C[2] = nullptr;
    hipLaunchKernelGGL(gemm_f, dim3(8, 40, 1), dim3(256), 0, stream, oF, 512);
}

// Round 10
// 298.282 us; speedup vs baseline: 1.0536x; 1.0536x over previous
//
#include <hip/hip_runtime.h>
#include <hip/hip_bf16.h>

#define B_  8
#define LQ  160
#define LK  160

typedef __attribute__((ext_vector_type(8))) short bf16x8;
typedef __attribute__((ext_vector_type(4))) float f32x4;

static __device__ __forceinline__ ushort f2bf(float f) {
    union { float f; unsigned u; } v; v.f = f;
    const unsigned r = (v.u + 0x7FFF + ((v.u >> 16) & 1)) >> 16;  // RNE
    return (ushort)r;
}

// ---------------------------------------------------------------------------
// fp32 -> bf16 cast for the scores-path inputs/weights. grid (640, 6).
// ---------------------------------------------------------------------------
struct CastArgs { const float4* src[6]; ushort4* dst[6]; int n[6]; };

__global__ __launch_bounds__(256) void cast_bf16k(CastArgs a)
{
    const int seg = blockIdx.y;
    const int i = blockIdx.x * 256 + threadIdx.x;
    if (i < a.n[seg]) {
        const float4 v = a.src[seg][i];
        ushort4 u;
        u.x = f2bf(v.x); u.y = f2bf(v.y); u.z = f2bf(v.z); u.w = f2bf(v.w);
        a.dst[seg][i] = u;
    }
}

// ---------------------------------------------------------------------------
// bf16 MFMA GEMM: C[m,n] = sum_k A[m,k]*W[n,k] + bias[n].
// A [1280,512] bf16 row-major, W [512,512] bf16 row-major.
// Block 256 thr = 4 waves; tile 64x64 (wave = 16 rows x 64 cols, 4 frags).
// 16x16x32 frags, direct-from-global (no LDS): A row=lane&15, k=(lane>>4)*8+j;
// B col=lane&15 (W row), same k; D col=lane&15, row=(lane>>4)*4+reg (m89).
// OUTBF=1 -> bf16 store (feeds next MFMA); else fp32 store.
// ---------------------------------------------------------------------------
struct MfmaOps { const ushort* A[2]; const ushort* W[2]; const float* Bi[2]; void* C[2]; };

template <int OUTBF>
__global__ __launch_bounds__(256) void mfma_g(MfmaOps ops)
{
    const int op = blockIdx.z;
    const ushort* __restrict__ A  = ops.A[op];
    const ushort* __restrict__ W  = ops.W[op];
    const float*  __restrict__ Bi = ops.Bi[op];

    const int m0 = blockIdx.y << 6;
    const int n0 = blockIdx.x << 6;
    const int tid  = threadIdx.x;
    const int wave = tid >> 6;
    const int lane = tid & 63;
    const int l16  = lane & 15;
    const int kg   = (lane >> 4) << 3;   // 0,8,16,24

    const ushort* Ap = A + (long)(m0 + (wave << 4) + l16) * 512 + kg;
    const ushort* Wp = W + (long)(n0 + l16) * 512 + kg;

    f32x4 acc[4] = {{0.f,0.f,0.f,0.f},{0.f,0.f,0.f,0.f},
                    {0.f,0.f,0.f,0.f},{0.f,0.f,0.f,0.f}};
    for (int k0 = 0; k0 < 512; k0 += 32) {
        const bf16x8 a = *(const bf16x8*)(Ap + k0);
#pragma unroll
        for (int nf = 0; nf < 4; nf++) {
            const bf16x8 b = *(const bf16x8*)(Wp + nf * (16 * 512) + k0);
            acc[nf] = __builtin_amdgcn_mfma_f32_16x16x32_bf16(a, b, acc[nf], 0, 0, 0);
        }
    }

    const int mrow = m0 + (wave << 4) + ((lane >> 4) << 2);
#pragma unroll
    for (int nf = 0; nf < 4; nf++) {
        const int n = n0 + (nf << 4) + l16;
        const float bias = Bi[n];
        if (OUTBF) {
            ushort* C = (ushort*)ops.C[op];
#pragma unroll
            for (int r = 0; r < 4; r++)
                C[(long)(mrow + r) * 512 + n] = f2bf(acc[nf][r] + bias);
        } else {
            float* C = (float*)ops.C[op];
#pragma unroll
            for (int r = 0; r < 4; r++)
                C[(long)(mrow + r) * 512 + n] = acc[nf][r] + bias;
        }
    }
}

// ---------------------------------------------------------------------------
// fp32 GEMM (precision-critical ops: vv, final linear). 64x64 tile, r7 version.
// ---------------------------------------------------------------------------
struct GOps {
    const float* A[3];
    const float* W[3];
    const float* Bi[3];
    float*       C[3];
};

__global__ __launch_bounds__(256) void gemm_f(GOps ops, int K)
{
    const int op = blockIdx.z;
    const float* __restrict__ A  = ops.A[op];
    const float* __restrict__ W  = ops.W[op];
    const float* __restrict__ Bi = ops.Bi[op];
    float* __restrict__       C  = ops.C[op];

    const int m0 = blockIdx.y << 6;
    const int n0 = blockIdx.x << 6;
    const int tid = threadIdx.x;
    const int tm  = tid >> 4;
    const int tn  = tid & 15;
    const int lr  = tid >> 2;
    const int lk4 = (tid & 3) << 2;

    __shared__ float As[16][64];
    __shared__ float Ws[16][64];

    float acc[4][4];
#pragma unroll
    for (int i = 0; i < 4; i++)
#pragma unroll
        for (int j = 0; j < 4; j++) acc[i][j] = 0.f;

    const float* Arow = A + (long)(m0 + lr) * 512 + lk4;
    const float* Wrow = W + (long)(n0 + lr) * K + lk4;
    float4 av = *(const float4*)(Arow);
    float4 wv = *(const float4*)(Wrow);

    for (int k0 = 0; k0 < K; k0 += 16) {
        __syncthreads();
        As[lk4 + 0][lr] = av.x; As[lk4 + 1][lr] = av.y;
        As[lk4 + 2][lr] = av.z; As[lk4 + 3][lr] = av.w;
        Ws[lk4 + 0][lr] = wv.x; Ws[lk4 + 1][lr] = wv.y;
        Ws[lk4 + 2][lr] = wv.z; Ws[lk4 + 3][lr] = wv.w;
        __syncthreads();
        if (k0 + 16 < K) {
            av = *(const float4*)(Arow + k0 + 16);
            wv = *(const float4*)(Wrow + k0 + 16);
        }
#pragma unroll
        for (int kk = 0; kk < 16; kk++) {
            const float4 a4 = *(const float4*)(&As[kk][tm << 2]);
            const float4 b4 = *(const float4*)(&Ws[kk][tn << 2]);
            const float aa[4] = {a4.x, a4.y, a4.z, a4.w};
            const float bb[4] = {b4.x, b4.y, b4.z, b4.w};
#pragma unroll
            for (int i = 0; i < 4; i++)
#pragma unroll
                for (int j = 0; j < 4; j++)
                    acc[i][j] = fmaf(aa[i], bb[j], acc[i][j]);
        }
    }

    const float4 bv = *(const float4*)(Bi + n0 + (tn << 2));
    const float bArr[4] = {bv.x, bv.y, bv.z, bv.w};

#pragma unroll
    for (int i = 0; i < 4; i++) {
        float4 vo;
        vo.x = acc[i][0] + bArr[0]; vo.y = acc[i][1] + bArr[1];
        vo.z = acc[i][2] + bArr[2]; vo.w = acc[i][3] + bArr[3];
        *(float4*)(C + (long)(m0 + (tm << 2) + i) * 512 + n0 + (tn << 2)) = vo;
    }
}

// ---------------------------------------------------------------------------
// Fused per-chunk merge projections (fp32, K=64), unchanged from r9.
// y0t[b][c][s][k][r]; y1p[m][c][s][r] (c*512 + s*8 + r).
// ---------------------------------------------------------------------------
__global__ __launch_bounds__(256) void y_proj(
    const float* __restrict__ x0, const float* __restrict__ wm0, const float* __restrict__ bm0,
    const float* __restrict__ x1, const float* __restrict__ wm1, const float* __restrict__ bm1,
    float* __restrict__ y0t, float* __restrict__ y1p)
{
    const int z   = blockIdx.z;
    const bool is1 = z >= 8;
    const int c   = is1 ? z - 8 : z;
    const float* A  = (is1 ? x1 : x0) + (c << 6);
    const float* W  = (is1 ? wm1 : wm0) + c * 32768;
    const float* Bi = (is1 ? bm1 : bm0) + (c << 9);

    const int m0 = blockIdx.y << 6;
    const int s0 = blockIdx.x << 3;
    const int tid = threadIdx.x;
    const int tm  = tid >> 4;
    const int tn  = tid & 15;
    const int lr  = tid >> 2;
    const int lk4 = (tid & 3) << 2;

    __shared__ float As[16][64];
    __shared__ float Ws[16][64];
    __shared__ float outT[4096];

    float acc[4][4];
#pragma unroll
    for (int i = 0; i < 4; i++)
#pragma unroll
        for (int j = 0; j < 4; j++) acc[i][j] = 0.f;

    const int wrow = ((lr & 7) << 6) + s0 + (lr >> 3);
    const float* Arow = A + (long)(m0 + lr) * 512 + lk4;
    const float* Wrow = W + (long)wrow * 64 + lk4;
    float4 av = *(const float4*)(Arow);
    float4 wv = *(const float4*)(Wrow);

    for (int k0 = 0; k0 < 64; k0 += 16) {
        __syncthreads();
        As[lk4 + 0][lr] = av.x; As[lk4 + 1][lr] = av.y;
        As[lk4 + 2][lr] = av.z; As[lk4 + 3][lr] = av.w;
        Ws[lk4 + 0][lr] = wv.x; Ws[lk4 + 1][lr] = wv.y;
        Ws[lk4 + 2][lr] = wv.z; Ws[lk4 + 3][lr] = wv.w;
        __syncthreads();
        if (k0 + 16 < 64) {
            av = *(const float4*)(Arow + k0 + 16);
            wv = *(const float4*)(Wrow + k0 + 16);
        }
#pragma unroll
        for (int kk = 0; kk < 16; kk++) {
            const float4 a4 = *(const float4*)(&As[kk][tm << 2]);
            const float4 b4 = *(const float4*)(&Ws[kk][tn << 2]);
            const float aa[4] = {a4.x, a4.y, a4.z, a4.w};
            const float bb[4] = {b4.x, b4.y, b4.z, b4.w};
#pragma unroll
            for (int i = 0; i < 4; i++)
#pragma unroll
                for (int j = 0; j < 4; j++)
                    acc[i][j] = fmaf(aa[i], bb[j], acc[i][j]);
        }
    }

    float bArr[4];
#pragma unroll
    for (int j = 0; j < 4; j++) {
        const int ln = (tn << 2) + j;
        bArr[j] = Bi[((ln & 7) << 6) + s0 + (ln >> 3)];
    }
    __syncthreads();
    if (is1) {
#pragma unroll
        for (int i = 0; i < 4; i++) {
            const int m8 = (tm << 2) + i;
#pragma unroll
            for (int j = 0; j < 4; j++) {
                const int ln = (tn << 2) + j;
                outT[(m8 << 6) + ((ln >> 3) << 3) + (ln & 7)] = acc[i][j] + bArr[j];
            }
        }
        __syncthreads();
#pragma unroll
        for (int p = 0; p < 4; p++) {
            const int idx = tid + (p << 8);
            const int m8  = idx >> 4;
            const int f4  = idx & 15;
            *(float4*)(y1p + (long)(m0 + m8) * 4096 + (c << 9) + (s0 << 3) + (f4 << 2))
                = *(const float4*)&outT[idx << 2];
        }
    } else {
#pragma unroll
        for (int i = 0; i < 4; i++) {
            const int k8 = (tm << 2) + i;
#pragma unroll
            for (int j = 0; j < 4; j++) {
                const int ln = (tn << 2) + j;
                outT[((ln >> 3) << 9) + (k8 << 3) + (ln & 7)] = acc[i][j] + bArr[j];
            }
        }
        __syncthreads();
#pragma unroll
        for (int p = 0; p < 4; p++) {
            const int s8  = (p << 1) + (tid >> 7);
            const int u4  = tid & 127;
            const int k8  = u4 >> 1;
            const int r   = (u4 & 1) << 2;
            const int m   = m0 + k8;
            const int bidx = m / 160;
            const int kmod = m - bidx * 160;
            const int s   = s0 + s8;
            float4* dst = (float4*)(y0t +
                (((long)(bidx * 8 + c) * 64 + s) * 160 + kmod) * 8 + r);
            *dst = *(const float4*)&outT[(s8 << 9) + (u4 << 2)];
        }
    }
}

// ---------------------------------------------------------------------------
// Per-(b, 4-q-tile, c) partial scores (r8 s_load version, 74 us best).
// y1/w_bo wave-uniform -> scalar path; y0 per-lane 2x float4 + prefetch.
// scores_p: [B][LQ][C][LK]
// ---------------------------------------------------------------------------
__global__ __launch_bounds__(192) void score_partial(
    const float* __restrict__ y1p, const float* __restrict__ y0t,
    const float* __restrict__ wbo, float* __restrict__ scores_p)
{
    const int id = blockIdx.x;
    const int c  = id & 7;
    const int j  = id >> 3;
    const int b  = j / 40;
    const int q0 = (j - b * 40) << 2;
    const int k  = threadIdx.x;
    const int kc = k < LK ? k : (LK - 1);

    const float* wb = wbo + (c << 6);
    const float* y1r0 = y1p + (long)(b * LQ + q0) * 4096 + (c << 9);
    const float* y1r1 = y1r0 + 4096;
    const float* y1r2 = y1r0 + 8192;
    const float* y1r3 = y1r0 + 12288;
    const float* ybc = y0t + (((long)(b * 8 + c) * 64) * 160 + kc) * 8;

    float num[4] = {0.f, 0.f, 0.f, 0.f};
    float den[4] = {0.f, 0.f, 0.f, 0.f};

    float4 a0 = *(const float4*)(ybc);
    float4 a1 = *(const float4*)(ybc + 4);
#pragma unroll 2
    for (int s = 0; s < 64; s++) {
        const float a[8] = {a0.x, a0.y, a0.z, a0.w, a1.x, a1.y, a1.z, a1.w};
        const int sn = (s + 1) & 63;
        a0 = *(const float4*)(ybc + (long)sn * 1280);
        a1 = *(const float4*)(ybc + (long)sn * 1280 + 4);
        const float w = wb[s];
        const int o = s << 3;
        {
            float zv = a[0] * y1r0[o];
            zv = fmaf(a[1], y1r0[o+1], zv); zv = fmaf(a[2], y1r0[o+2], zv);
            zv = fmaf(a[3], y1r0[o+3], zv); zv = fmaf(a[4], y1r0[o+4], zv);
            zv = fmaf(a[5], y1r0[o+5], zv); zv = fmaf(a[6], y1r0[o+6], zv);
            zv = fmaf(a[7], y1r0[o+7], zv);
            const float az = fabsf(zv);
            num[0] = fmaf(copysignf(__builtin_amdgcn_sqrtf(az), zv), w, num[0]);
            den[0] += az;
        }
        {
            float zv = a[0] * y1r1[o];
            zv = fmaf(a[1], y1r1[o+1], zv); zv = fmaf(a[2], y1r1[o+2], zv);
            zv = fmaf(a[3], y1r1[o+3], zv); zv = fmaf(a[4], y1r1[o+4], zv);
            zv = fmaf(a[5], y1r1[o+5], zv); zv = fmaf(a[6], y1r1[o+6], zv);
            zv = fmaf(a[7], y1r1[o+7], zv);
            const float az = fabsf(zv);
            num[1] = fmaf(copysignf(__builtin_amdgcn_sqrtf(az), zv), w, num[1]);
            den[1] += az;
        }
        {
            float zv = a[0] * y1r2[o];
            zv = fmaf(a[1], y1r2[o+1], zv); zv = fmaf(a[2], y1r2[o+2], zv);
            zv = fmaf(a[3], y1r2[o+3], zv); zv = fmaf(a[4], y1r2[o+4], zv);
            zv = fmaf(a[5], y1r2[o+5], zv); zv = fmaf(a[6], y1r2[o+6], zv);
            zv = fmaf(a[7], y1r2[o+7], zv);
            const float az = fabsf(zv);
            num[2] = fmaf(copysignf(__builtin_amdgcn_sqrtf(az), zv), w, num[2]);
            den[2] += az;
        }
        {
            float zv = a[0] * y1r3[o];
            zv = fmaf(a[1], y1r3[o+1], zv); zv = fmaf(a[2], y1r3[o+2], zv);
            zv = fmaf(a[3], y1r3[o+3], zv); zv = fmaf(a[4], y1r3[o+4], zv);
            zv = fmaf(a[5], y1r3[o+5], zv); zv = fmaf(a[6], y1r3[o+6], zv);
            zv = fmaf(a[7], y1r3[o+7], zv);
            const float az = fabsf(zv);
            num[3] = fmaf(copysignf(__builtin_amdgcn_sqrtf(az), zv), w, num[3]);
            den[3] += az;
        }
    }
    if (k < LK) {
#pragma unroll
        for (int q = 0; q < 4; q++)
            scores_p[(((long)(b * LQ + q0 + q)) * 8 + c) * 160 + k] =
                num[q] / fmaxf(__builtin_amdgcn_sqrtf(den[q]), 1e-12f);
    }
}

// ---------------------------------------------------------------------------
// Sum partials over c, softmax over k, att@vv, write attedT [B][512][LQ].
// ---------------------------------------------------------------------------
__global__ __launch_bounds__(256) void softmax_attv(
    const float* __restrict__ scores_p, const float* __restrict__ vv,
    float* __restrict__ attedT)
{
    const int b  = blockIdx.y;
    const int q0 = blockIdx.x << 2;
    const int tid = threadIdx.x;

    __shared__ float scs[4][160];
    __shared__ float invd[4];

    for (int t = tid; t < 640; t += 256) {
        const int q = t / 160;
        const int k = t - q * 160;
        const float* sp = scores_p + ((long)(b * LQ + q0 + q)) * 1280 + k;
        float s = 0.f;
#pragma unroll
        for (int c = 0; c < 8; c++) s += sp[c * 160];
        scs[q][k] = s;
    }
    __syncthreads();

    const int w    = tid >> 6;
    const int lane = tid & 63;
    {
        const int q = w;
        float m = -1e30f;
        for (int kk = lane; kk < LK; kk += 64) m = fmaxf(m, scs[q][kk]);
#pragma unroll
        for (int off = 32; off; off >>= 1) m = fmaxf(m, __shfl_xor(m, off, 64));
        float sum = 0.f;
        for (int kk = lane; kk < LK; kk += 64) {
            const float e = __expf(scs[q][kk] - m);
            scs[q][kk] = e;
            sum += e;
        }
#pragma unroll
        for (int off = 32; off; off >>= 1) sum += __shfl_xor(sum, off, 64);
        if (lane == 0) invd[q] = 1.f / sum;
    }
    __syncthreads();

    float acc[2][4] = {{0.f,0.f,0.f,0.f},{0.f,0.f,0.f,0.f}};
    const float* vb = vv + (long)b * (LK * 512);
    for (int kk = 0; kk < LK; kk++) {
        const float* vr = vb + kk * 512;
        const float p0 = scs[0][kk], p1 = scs[1][kk];
        const float p2 = scs[2][kk], p3 = scs[3][kk];
        const float v0 = vr[tid], v1 = vr[tid + 256];
        acc[0][0] = fmaf(p0, v0, acc[0][0]); acc[0][1] = fmaf(p1, v0, acc[0][1]);
        acc[0][2] = fmaf(p2, v0, acc[0][2]); acc[0][3] = fmaf(p3, v0, acc[0][3]);
        acc[1][0] = fmaf(p0, v1, acc[1][0]); acc[1][1] = fmaf(p1, v1, acc[1][1]);
        acc[1][2] = fmaf(p2, v1, acc[1][2]); acc[1][3] = fmaf(p3, v1, acc[1][3]);
    }
#pragma unroll
    for (int j = 0; j < 2; j++) {
        const int h = tid + (j << 8);
#pragma unroll
        for (int q = 0; q < 4; q++)
            attedT[((long)b * 512 + h) * 160 + q0 + q] = acc[j][q] * invd[q];
    }
}

// ---------------------------------------------------------------------------
extern "C" void kernel_launch(void* const* d_in, const int* in_sizes, int n_in,
                              void* d_out, int out_size, void* d_ws, size_t ws_size,
                              hipStream_t stream) {
    const float* v    = (const float*)d_in[0];
    const float* kin  = (const float*)d_in[1];
    const float* q    = (const float*)d_in[2];
    const float* w_v  = (const float*)d_in[3];
    const float* b_v  = (const float*)d_in[4];
    const float* w_k  = (const float*)d_in[5];
    const float* b_k  = (const float*)d_in[6];
    const float* w_q  = (const float*)d_in[7];
    const float* b_q  = (const float*)d_in[8];
    const float* w0   = (const float*)d_in[9];
    const float* b0   = (const float*)d_in[10];
    const float* w1   = (const float*)d_in[11];
    const float* b1   = (const float*)d_in[12];
    const float* wm0  = (const float*)d_in[13];
    const float* bm0  = (const float*)d_in[14];
    const float* wm1  = (const float*)d_in[15];
    const float* bm1  = (const float*)d_in[16];
    const float* w_bo = (const float*)d_in[17];
    (void)d_in[18];  // b_bo unused: softmax is shift-invariant
    const float* w_m  = (const float*)d_in[19];
    const float* b_m  = (const float*)d_in[20];

    float* ws       = (float*)d_ws;
    float* vv       = ws;                       // 655360 f
    ushort* kbf     = (ushort*)(ws + 655360);   // 655360 bf16
    ushort* qbf     = kbf + 655360;
    ushort* kkbf    = (ushort*)(ws + 1310720);  // 655360 bf16
    ushort* qqbf    = kkbf + 655360;
    float* x0       = ws + 1966080;             // 655360 f
    float* x1       = ws + 2621440;             // 655360 f
    float* y1p      = ws + 3276800;             // 5242880 f  [m][c][s][r]
    float* y0t      = ws + 8519680;             // 5242880 f  [B][c][s][k][r]
    float* attedT   = ws + 13762560;            // 655360 f   [B][512][LQ]
    ushort* wkbf    = (ushort*)(ws + 14417920); // 262144 bf16 each
    ushort* wqbf    = wkbf + 262144;
    ushort* w0bf    = wkbf + 524288;
    ushort* w1bf    = wkbf + 786432;            // end: ws + 14942208 floats
    float* scores_p = ws + 655360;              // 1638400 f, aliases bf16/x0-head (dead)

    // 1. cast scores-path inputs/weights to bf16
    CastArgs ca;
    ca.src[0] = (const float4*)kin; ca.dst[0] = (ushort4*)kbf;  ca.n[0] = 163840;
    ca.src[1] = (const float4*)q;   ca.dst[1] = (ushort4*)qbf;  ca.n[1] = 163840;
    ca.src[2] = (const float4*)w_k; ca.dst[2] = (ushort4*)wkbf; ca.n[2] = 65536;
    ca.src[3] = (const float4*)w_q; ca.dst[3] = (ushort4*)wqbf; ca.n[3] = 65536;
    ca.src[4] = (const float4*)w0;  ca.dst[4] = (ushort4*)w0bf; ca.n[4] = 65536;
    ca.src[5] = (const float4*)w1;  ca.dst[5] = (ushort4*)w1bf; ca.n[5] = 65536;
    hipLaunchKernelGGL(cast_bf16k, dim3(640, 6), dim3(256), 0, stream, ca);

    // 2. vv = v@w_v + b_v (fp32, precision-critical)
    GOps oV;
    oV.A[0] = v; oV.W[0] = w_v; oV.Bi[0] = b_v; oV.C[0] = vv;
    oV.A[1] = oV.A[2] = nullptr; oV.W[1] = oV.W[2] = nullptr;
    oV.Bi[1] = oV.Bi[2] = nullptr; oV.C[1] = oV.C[2] = nullptr;
    hipLaunchKernelGGL(gemm_f, dim3(8, 20, 1), dim3(256), 0, stream, oV, 512);

    // 3. kk,qq via bf16 MFMA (bf16 out)
    MfmaOps mA;
    mA.A[0] = kbf; mA.W[0] = wkbf; mA.Bi[0] = b_k; mA.C[0] = kkbf;
    mA.A[1] = qbf; mA.W[1] = wqbf; mA.Bi[1] = b_q; mA.C[1] = qqbf;
    hipLaunchKernelGGL((mfma_g<1>), dim3(8, 20, 2), dim3(256), 0, stream, mA);

    // 4. x0,x1 via bf16 MFMA (fp32 out)
    MfmaOps mB;
    mB.A[0] = kkbf; mB.W[0] = w0bf; mB.Bi[0] = b0; mB.C[0] = x0;
    mB.A[1] = qqbf; mB.W[1] = w1bf; mB.Bi[1] = b1; mB.C[1] = x1;
    hipLaunchKernelGGL((mfma_g<0>), dim3(8, 20, 2), dim3(256), 0, stream, mB);

    // 5. merge projections (fp32)
    hipLaunchKernelGGL(y_proj, dim3(8, 20, 16), dim3(256), 0, stream,
                       x0, wm0, bm0, x1, wm1, bm1, y0t, y1p);

    // 6. partial scores
    hipLaunchKernelGGL(score_partial, dim3(2560), dim3(192), 0, stream,
                       y1p, y0t, w_bo, scores_p);

    // 7. softmax + att@vv
    hipLaunchKernelGGL(softmax_attv, dim3(40, 8), dim3(256), 0, stream,
                       scores_p, vv, attedT);

    // 8. final linear (fp32, precision-critical)
    GOps oF;
    oF.A[0] = attedT; oF.W[0] = w_m; oF.Bi[0] = b_m; oF.C[0] = (float*)d_out;
    oF.A[1] = oF.A[2] = nullptr; oF.W[1] = oF.W[2] = nullptr;
    oF.Bi[1] = oF.Bi[2] = nullptr; oF.C[1] = oF.C[2] = nullptr;
    hipLaunchKernelGGL(gemm_f, dim3(8, 20, 1), dim3(256), 0, stream, oF, 512);
}

// Round 12
// 260.466 us; speedup vs baseline: 1.2066x; 1.1452x over previous
//
#include <hip/hip_runtime.h>
#include <hip/hip_bf16.h>

#define B_  8
#define LQ  160
#define LK  160

typedef __attribute__((ext_vector_type(8))) short bf16x8;
typedef __attribute__((ext_vector_type(4))) float f32x4;

static __device__ __forceinline__ ushort f2bf(float f) {
    union { float f; unsigned u; } v; v.f = f;
    const unsigned r = (v.u + 0x7FFF + ((v.u >> 16) & 1)) >> 16;  // RNE
    return (ushort)r;
}

// ---------------------------------------------------------------------------
// fp32 -> bf16 cast for the scores-path inputs/weights. grid (640, 6).
// ---------------------------------------------------------------------------
struct CastArgs { const float4* src[6]; ushort4* dst[6]; int n[6]; };

__global__ __launch_bounds__(256) void cast_bf16k(CastArgs a)
{
    const int seg = blockIdx.y;
    const int i = blockIdx.x * 256 + threadIdx.x;
    if (i < a.n[seg]) {
        const float4 v = a.src[seg][i];
        ushort4 u;
        u.x = f2bf(v.x); u.y = f2bf(v.y); u.z = f2bf(v.z); u.w = f2bf(v.w);
        a.dst[seg][i] = u;
    }
}

// ---------------------------------------------------------------------------
// bf16 MFMA GEMM (verified layout, r10): C = A@W^T + bias.
// A [1280,512] bf16, W [512,512] bf16. 64x64 tile, 4 waves.
// ---------------------------------------------------------------------------
struct MfmaOps { const ushort* A[2]; const ushort* W[2]; const float* Bi[2]; void* C[2]; };

template <int OUTBF>
__global__ __launch_bounds__(256) void mfma_g(MfmaOps ops)
{
    const int op = blockIdx.z;
    const ushort* __restrict__ A  = ops.A[op];
    const ushort* __restrict__ W  = ops.W[op];
    const float*  __restrict__ Bi = ops.Bi[op];

    const int m0 = blockIdx.y << 6;
    const int n0 = blockIdx.x << 6;
    const int tid  = threadIdx.x;
    const int wave = tid >> 6;
    const int lane = tid & 63;
    const int l16  = lane & 15;
    const int kg   = (lane >> 4) << 3;

    const ushort* Ap = A + (long)(m0 + (wave << 4) + l16) * 512 + kg;
    const ushort* Wp = W + (long)(n0 + l16) * 512 + kg;

    f32x4 acc[4] = {{0.f,0.f,0.f,0.f},{0.f,0.f,0.f,0.f},
                    {0.f,0.f,0.f,0.f},{0.f,0.f,0.f,0.f}};
    for (int k0 = 0; k0 < 512; k0 += 32) {
        const bf16x8 a = *(const bf16x8*)(Ap + k0);
#pragma unroll
        for (int nf = 0; nf < 4; nf++) {
            const bf16x8 b = *(const bf16x8*)(Wp + nf * (16 * 512) + k0);
            acc[nf] = __builtin_amdgcn_mfma_f32_16x16x32_bf16(a, b, acc[nf], 0, 0, 0);
        }
    }

    const int mrow = m0 + (wave << 4) + ((lane >> 4) << 2);
#pragma unroll
    for (int nf = 0; nf < 4; nf++) {
        const int n = n0 + (nf << 4) + l16;
        const float bias = Bi[n];
        if (OUTBF) {
            ushort* C = (ushort*)ops.C[op];
#pragma unroll
            for (int r = 0; r < 4; r++)
                C[(long)(mrow + r) * 512 + n] = f2bf(acc[nf][r] + bias);
        } else {
            float* C = (float*)ops.C[op];
#pragma unroll
            for (int r = 0; r < 4; r++)
                C[(long)(mrow + r) * 512 + n] = acc[nf][r] + bias;
        }
    }
}

// ---------------------------------------------------------------------------
// fp32 GEMM (precision-critical ops: vv, final linear). 64x64 tile.
// ---------------------------------------------------------------------------
struct GOps {
    const float* A[3];
    const float* W[3];
    const float* Bi[3];
    float*       C[3];
};

__global__ __launch_bounds__(256) void gemm_f(GOps ops, int K)
{
    const int op = blockIdx.z;
    const float* __restrict__ A  = ops.A[op];
    const float* __restrict__ W  = ops.W[op];
    const float* __restrict__ Bi = ops.Bi[op];
    float* __restrict__       C  = ops.C[op];

    const int m0 = blockIdx.y << 6;
    const int n0 = blockIdx.x << 6;
    const int tid = threadIdx.x;
    const int tm  = tid >> 4;
    const int tn  = tid & 15;
    const int lr  = tid >> 2;
    const int lk4 = (tid & 3) << 2;

    __shared__ float As[16][64];
    __shared__ float Ws[16][64];

    float acc[4][4];
#pragma unroll
    for (int i = 0; i < 4; i++)
#pragma unroll
        for (int j = 0; j < 4; j++) acc[i][j] = 0.f;

    const float* Arow = A + (long)(m0 + lr) * 512 + lk4;
    const float* Wrow = W + (long)(n0 + lr) * K + lk4;
    float4 av = *(const float4*)(Arow);
    float4 wv = *(const float4*)(Wrow);

    for (int k0 = 0; k0 < K; k0 += 16) {
        __syncthreads();
        As[lk4 + 0][lr] = av.x; As[lk4 + 1][lr] = av.y;
        As[lk4 + 2][lr] = av.z; As[lk4 + 3][lr] = av.w;
        Ws[lk4 + 0][lr] = wv.x; Ws[lk4 + 1][lr] = wv.y;
        Ws[lk4 + 2][lr] = wv.z; Ws[lk4 + 3][lr] = wv.w;
        __syncthreads();
        if (k0 + 16 < K) {
            av = *(const float4*)(Arow + k0 + 16);
            wv = *(const float4*)(Wrow + k0 + 16);
        }
#pragma unroll
        for (int kk = 0; kk < 16; kk++) {
            const float4 a4 = *(const float4*)(&As[kk][tm << 2]);
            const float4 b4 = *(const float4*)(&Ws[kk][tn << 2]);
            const float aa[4] = {a4.x, a4.y, a4.z, a4.w};
            const float bb[4] = {b4.x, b4.y, b4.z, b4.w};
#pragma unroll
            for (int i = 0; i < 4; i++)
#pragma unroll
                for (int j = 0; j < 4; j++)
                    acc[i][j] = fmaf(aa[i], bb[j], acc[i][j]);
        }
    }

    const float4 bv = *(const float4*)(Bi + n0 + (tn << 2));
    const float bArr[4] = {bv.x, bv.y, bv.z, bv.w};

#pragma unroll
    for (int i = 0; i < 4; i++) {
        float4 vo;
        vo.x = acc[i][0] + bArr[0]; vo.y = acc[i][1] + bArr[1];
        vo.z = acc[i][2] + bArr[2]; vo.w = acc[i][3] + bArr[3];
        *(float4*)(C + (long)(m0 + (tm << 2) + i) * 512 + n0 + (tn << 2)) = vo;
    }
}

// ---------------------------------------------------------------------------
// Fused per-chunk merge projections (fp32 core, K=64). z<8 -> y0, else y1.
// BOTH outputs share one bf16 layout: yf[b][c][s][row][r]
// (row = k for y0-source, q for y1-source; elem stride r=1, row=8, s=1280).
// Remapped columns: col ln -> (s = s0+(ln>>3), r = ln&7); LDS transpose then
// contiguous 1KB bf16 runs per s (piecewise at b boundary).
// ---------------------------------------------------------------------------
__global__ __launch_bounds__(256) void y_proj(
    const float* __restrict__ x0, const float* __restrict__ wm0, const float* __restrict__ bm0,
    const float* __restrict__ x1, const float* __restrict__ wm1, const float* __restrict__ bm1,
    ushort* __restrict__ y0f, ushort* __restrict__ y1f)
{
    const int z   = blockIdx.z;
    const bool is1 = z >= 8;
    const int c   = is1 ? z - 8 : z;
    const float* A  = (is1 ? x1 : x0) + (c << 6);
    const float* W  = (is1 ? wm1 : wm0) + c * 32768;
    const float* Bi = (is1 ? bm1 : bm0) + (c << 9);
    ushort* __restrict__ dstT = is1 ? y1f : y0f;

    const int m0 = blockIdx.y << 6;
    const int s0 = blockIdx.x << 3;
    const int tid = threadIdx.x;
    const int tm  = tid >> 4;
    const int tn  = tid & 15;
    const int lr  = tid >> 2;
    const int lk4 = (tid & 3) << 2;

    __shared__ float As[16][64];
    __shared__ float Ws[16][64];
    __shared__ float outT[4096];   // [s8][row8][r]

    float acc[4][4];
#pragma unroll
    for (int i = 0; i < 4; i++)
#pragma unroll
        for (int j = 0; j < 4; j++) acc[i][j] = 0.f;

    const int wrow = ((lr & 7) << 6) + s0 + (lr >> 3);
    const float* Arow = A + (long)(m0 + lr) * 512 + lk4;
    const float* Wrow = W + (long)wrow * 64 + lk4;
    float4 av = *(const float4*)(Arow);
    float4 wv = *(const float4*)(Wrow);

    for (int k0 = 0; k0 < 64; k0 += 16) {
        __syncthreads();
        As[lk4 + 0][lr] = av.x; As[lk4 + 1][lr] = av.y;
        As[lk4 + 2][lr] = av.z; As[lk4 + 3][lr] = av.w;
        Ws[lk4 + 0][lr] = wv.x; Ws[lk4 + 1][lr] = wv.y;
        Ws[lk4 + 2][lr] = wv.z; Ws[lk4 + 3][lr] = wv.w;
        __syncthreads();
        if (k0 + 16 < 64) {
            av = *(const float4*)(Arow + k0 + 16);
            wv = *(const float4*)(Wrow + k0 + 16);
        }
#pragma unroll
        for (int kk = 0; kk < 16; kk++) {
            const float4 a4 = *(const float4*)(&As[kk][tm << 2]);
            const float4 b4 = *(const float4*)(&Ws[kk][tn << 2]);
            const float aa[4] = {a4.x, a4.y, a4.z, a4.w};
            const float bb[4] = {b4.x, b4.y, b4.z, b4.w};
#pragma unroll
            for (int i = 0; i < 4; i++)
#pragma unroll
                for (int j = 0; j < 4; j++)
                    acc[i][j] = fmaf(aa[i], bb[j], acc[i][j]);
        }
    }

    float bArr[4];
#pragma unroll
    for (int j = 0; j < 4; j++) {
        const int ln = (tn << 2) + j;
        bArr[j] = Bi[((ln & 7) << 6) + s0 + (ln >> 3)];
    }
    __syncthreads();
#pragma unroll
    for (int i = 0; i < 4; i++) {
        const int r8 = (tm << 2) + i;           // row-in-tile
#pragma unroll
        for (int j = 0; j < 4; j++) {
            const int ln = (tn << 2) + j;
            outT[((ln >> 3) << 9) + (r8 << 3) + (ln & 7)] = acc[i][j] + bArr[j];
        }
    }
    __syncthreads();
    // write 8 runs (one per s8) of 512 bf16 (1KB); 2 runs per pass
#pragma unroll
    for (int p = 0; p < 4; p++) {
        const int s8  = (p << 1) + (tid >> 7);
        const int u4  = tid & 127;              // 4-elem group within run
        const int r8  = u4 >> 1;
        const int r   = (u4 & 1) << 2;
        const int m   = m0 + r8;
        const int bidx = m / 160;
        const int rmod = m - bidx * 160;
        const int s   = s0 + s8;
        const float* src = &outT[(s8 << 9) + (u4 << 2)];
        ushort4 u;
        u.x = f2bf(src[0]); u.y = f2bf(src[1]);
        u.z = f2bf(src[2]); u.w = f2bf(src[3]);
        *(ushort4*)(dstT + (((long)(bidx * 8 + c) * 64 + s) * 160 + rmod) * 8 + r) = u;
    }
}

// ---------------------------------------------------------------------------
// MFMA score kernel: z[q,k] per (c,s) via matrix cores, nonlinearity on VALU.
// Grid 640 = qt(10) x b(8) x c(8), c fastest (XCD-local y0f slab).
// Block 320 = 5 waves; wave w owns k-tiles {2w, 2w+1}; block owns q-tile qt.
// Frags: A=y1f[s][q0+l16][r0..7], B=y0f[s][k0+l16][r0..7]; r lives in k-slots
// 0..7 (lanes 16-63 zero). D: col(k)=lane&15, row(q)=(lane>>4)*4+reg (m89).
// num/den accumulate in D layout; w[s] by __shfl broadcast (no SMEM in loop).
// scores_p: [B][LQ][C][LK] fp32.
// ---------------------------------------------------------------------------
__global__ __launch_bounds__(320) void score_mfma(
    const ushort* __restrict__ y1f, const ushort* __restrict__ y0f,
    const float* __restrict__ wbo, float* __restrict__ scores_p)
{
    const int bid = blockIdx.x;
    const int c  = bid & 7;
    const int b  = (bid >> 3) & 7;
    const int qt = bid >> 6;
    const int tid  = threadIdx.x;
    const int wave = tid >> 6;
    const int lane = tid & 63;
    const int l16  = lane & 15;
    const int g    = lane >> 4;
    const int q0   = qt << 4;
    const int k0   = wave << 5;          // 2 k-tiles: [k0, k0+32)

    const long cbase = (long)(b * 8 + c) * 81920;   // 64*160*8 elements
    const float wreg = wbo[(c << 6) + lane];        // lane s holds w[s]

    f32x4 num0 = {0.f,0.f,0.f,0.f}, den0 = {0.f,0.f,0.f,0.f};
    f32x4 num1 = {0.f,0.f,0.f,0.f}, den1 = {0.f,0.f,0.f,0.f};
    const f32x4 zc = {0.f,0.f,0.f,0.f};
    const bf16x8 zv8 = {0,0,0,0,0,0,0,0};

    for (int s = 0; s < 64; s++) {
        const float w = __shfl(wreg, s, 64);
        const ushort* row = y1f + cbase + (long)s * 1280;
        const ushort* row0 = y0f + cbase + (long)s * 1280;
        bf16x8 a = zv8, b0 = zv8, b1 = zv8;
        if (g == 0) {
            a  = *(const bf16x8*)(row  + (q0 + l16) * 8);
            b0 = *(const bf16x8*)(row0 + (k0 + l16) * 8);
            b1 = *(const bf16x8*)(row0 + (k0 + 16 + l16) * 8);
        }
        const f32x4 z0 = __builtin_amdgcn_mfma_f32_16x16x32_bf16(a, b0, zc, 0, 0, 0);
        const f32x4 z1 = __builtin_amdgcn_mfma_f32_16x16x32_bf16(a, b1, zc, 0, 0, 0);
#pragma unroll
        for (int r4 = 0; r4 < 4; r4++) {
            const float zz0 = z0[r4];
            const float az0 = fabsf(zz0);
            num0[r4] = fmaf(copysignf(__builtin_amdgcn_sqrtf(az0), zz0), w, num0[r4]);
            den0[r4] += az0;
            const float zz1 = z1[r4];
            const float az1 = fabsf(zz1);
            num1[r4] = fmaf(copysignf(__builtin_amdgcn_sqrtf(az1), zz1), w, num1[r4]);
            den1[r4] += az1;
        }
    }

#pragma unroll
    for (int r4 = 0; r4 < 4; r4++) {
        const int q = q0 + (g << 2) + r4;
        const long rowb = ((long)(b * LQ + q) * 8 + c) * 160;
        scores_p[rowb + k0 + l16] =
            num0[r4] / fmaxf(__builtin_amdgcn_sqrtf(den0[r4]), 1e-12f);
        scores_p[rowb + k0 + 16 + l16] =
            num1[r4] / fmaxf(__builtin_amdgcn_sqrtf(den1[r4]), 1e-12f);
    }
}

// ---------------------------------------------------------------------------
// Sum partials over c, softmax over k, att@vv, write attedT [B][512][LQ].
// ---------------------------------------------------------------------------
__global__ __launch_bounds__(256) void softmax_attv(
    const float* __restrict__ scores_p, const float* __restrict__ vv,
    float* __restrict__ attedT)
{
    const int b  = blockIdx.y;
    const int q0 = blockIdx.x << 2;
    const int tid = threadIdx.x;

    __shared__ float scs[4][160];
    __shared__ float invd[4];

    for (int t = tid; t < 640; t += 256) {
        const int q = t / 160;
        const int k = t - q * 160;
        const float* sp = scores_p + ((long)(b * LQ + q0 + q)) * 1280 + k;
        float s = 0.f;
#pragma unroll
        for (int c = 0; c < 8; c++) s += sp[c * 160];
        scs[q][k] = s;
    }
    __syncthreads();

    const int w    = tid >> 6;
    const int lane = tid & 63;
    {
        const int q = w;
        float m = -1e30f;
        for (int kk = lane; kk < LK; kk += 64) m = fmaxf(m, scs[q][kk]);
#pragma unroll
        for (int off = 32; off; off >>= 1) m = fmaxf(m, __shfl_xor(m, off, 64));
        float sum = 0.f;
        for (int kk = lane; kk < LK; kk += 64) {
            const float e = __expf(scs[q][kk] - m);
            scs[q][kk] = e;
            sum += e;
        }
#pragma unroll
        for (int off = 32; off; off >>= 1) sum += __shfl_xor(sum, off, 64);
        if (lane == 0) invd[q] = 1.f / sum;
    }
    __syncthreads();

    float acc[2][4] = {{0.f,0.f,0.f,0.f},{0.f,0.f,0.f,0.f}};
    const float* vb = vv + (long)b * (LK * 512);
    for (int kk = 0; kk < LK; kk++) {
        const float* vr = vb + kk * 512;
        const float p0 = scs[0][kk], p1 = scs[1][kk];
        const float p2 = scs[2][kk], p3 = scs[3][kk];
        const float v0 = vr[tid], v1 = vr[tid + 256];
        acc[0][0] = fmaf(p0, v0, acc[0][0]); acc[0][1] = fmaf(p1, v0, acc[0][1]);
        acc[0][2] = fmaf(p2, v0, acc[0][2]); acc[0][3] = fmaf(p3, v0, acc[0][3]);
        acc[1][0] = fmaf(p0, v1, acc[1][0]); acc[1][1] = fmaf(p1, v1, acc[1][1]);
        acc[1][2] = fmaf(p2, v1, acc[1][2]); acc[1][3] = fmaf(p3, v1, acc[1][3]);
    }
#pragma unroll
    for (int j = 0; j < 2; j++) {
        const int h = tid + (j << 8);
#pragma unroll
        for (int q = 0; q < 4; q++)
            attedT[((long)b * 512 + h) * 160 + q0 + q] = acc[j][q] * invd[q];
    }
}

// ---------------------------------------------------------------------------
extern "C" void kernel_launch(void* const* d_in, const int* in_sizes, int n_in,
                              void* d_out, int out_size, void* d_ws, size_t ws_size,
                              hipStream_t stream) {
    const float* v    = (const float*)d_in[0];
    const float* kin  = (const float*)d_in[1];
    const float* q    = (const float*)d_in[2];
    const float* w_v  = (const float*)d_in[3];
    const float* b_v  = (const float*)d_in[4];
    const float* w_k  = (const float*)d_in[5];
    const float* b_k  = (const float*)d_in[6];
    const float* w_q  = (const float*)d_in[7];
    const float* b_q  = (const float*)d_in[8];
    const float* w0   = (const float*)d_in[9];
    const float* b0   = (const float*)d_in[10];
    const float* w1   = (const float*)d_in[11];
    const float* b1   = (const float*)d_in[12];
    const float* wm0  = (const float*)d_in[13];
    const float* bm0  = (const float*)d_in[14];
    const float* wm1  = (const float*)d_in[15];
    const float* bm1  = (const float*)d_in[16];
    const float* w_bo = (const float*)d_in[17];
    (void)d_in[18];  // b_bo unused: softmax is shift-invariant
    const float* w_m  = (const float*)d_in[19];
    const float* b_m  = (const float*)d_in[20];

    float* ws       = (float*)d_ws;
    float* vv       = ws;                       // [0, 655360)
    ushort* kbf     = (ushort*)(ws + 655360);   // 655360 us + 655360 us
    ushort* qbf     = kbf + 655360;
    ushort* kkbf    = (ushort*)(ws + 1310720);
    ushort* qqbf    = kkbf + 655360;
    float* x0       = ws + 1966080;
    float* x1       = ws + 2621440;
    ushort* y1f     = (ushort*)(ws + 3276800);  // 5242880 ushorts (2621440 f)
    ushort* y0f     = (ushort*)(ws + 5898240);  // 5242880 ushorts
    float* attedT   = ws + 8519680;             // 655360
    float* scores_p = ws + 9175040;             // 1638400
    ushort* wkbf    = (ushort*)(ws + 10813440); // 4 x 262144 ushorts
    ushort* wqbf    = wkbf + 262144;
    ushort* w0bf    = wkbf + 524288;
    ushort* w1bf    = wkbf + 786432;            // ends ws + 11337728 floats

    // 1. cast scores-path inputs/weights to bf16
    CastArgs ca;
    ca.src[0] = (const float4*)kin; ca.dst[0] = (ushort4*)kbf;  ca.n[0] = 163840;
    ca.src[1] = (const float4*)q;   ca.dst[1] = (ushort4*)qbf;  ca.n[1] = 163840;
    ca.src[2] = (const float4*)w_k; ca.dst[2] = (ushort4*)wkbf; ca.n[2] = 65536;
    ca.src[3] = (const float4*)w_q; ca.dst[3] = (ushort4*)wqbf; ca.n[3] = 65536;
    ca.src[4] = (const float4*)w0;  ca.dst[4] = (ushort4*)w0bf; ca.n[4] = 65536;
    ca.src[5] = (const float4*)w1;  ca.dst[5] = (ushort4*)w1bf; ca.n[5] = 65536;
    hipLaunchKernelGGL(cast_bf16k, dim3(640, 6), dim3(256), 0, stream, ca);

    // 2. vv = v@w_v + b_v (fp32, precision-critical)
    GOps oV;
    oV.A[0] = v; oV.W[0] = w_v; oV.Bi[0] = b_v; oV.C[0] = vv;
    oV.A[1] = oV.A[2] = nullptr; oV.W[1] = oV.W[2] = nullptr;
    oV.Bi[1] = oV.Bi[2] = nullptr; oV.C[1] = oV.C[2] = nullptr;
    hipLaunchKernelGGL(gemm_f, dim3(8, 20, 1), dim3(256), 0, stream, oV, 512);

    // 3. kk,qq via bf16 MFMA (bf16 out)
    MfmaOps mA;
    mA.A[0] = kbf; mA.W[0] = wkbf; mA.Bi[0] = b_k; mA.C[0] = kkbf;
    mA.A[1] = qbf; mA.W[1] = wqbf; mA.Bi[1] = b_q; mA.C[1] = qqbf;
    hipLaunchKernelGGL((mfma_g<1>), dim3(8, 20, 2), dim3(256), 0, stream, mA);

    // 4. x0,x1 via bf16 MFMA (fp32 out)
    MfmaOps mB;
    mB.A[0] = kkbf; mB.W[0] = w0bf; mB.Bi[0] = b0; mB.C[0] = x0;
    mB.A[1] = qqbf; mB.W[1] = w1bf; mB.Bi[1] = b1; mB.C[1] = x1;
    hipLaunchKernelGGL((mfma_g<0>), dim3(8, 20, 2), dim3(256), 0, stream, mB);

    // 5. merge projections (fp32 core, bf16 fragment-layout output)
    hipLaunchKernelGGL(y_proj, dim3(8, 20, 16), dim3(256), 0, stream,
                       x0, wm0, bm0, x1, wm1, bm1, y0f, y1f);

    // 6. scores via MFMA
    hipLaunchKernelGGL(score_mfma, dim3(640), dim3(320), 0, stream,
                       y1f, y0f, w_bo, scores_p);

    // 7. softmax + att@vv
    hipLaunchKernelGGL(softmax_attv, dim3(40, 8), dim3(256), 0, stream,
                       scores_p, vv, attedT);

    // 8. final linear (fp32, precision-critical)
    GOps oF;
    oF.A[0] = attedT; oF.W[0] = w_m; oF.Bi[0] = b_m; oF.C[0] = (float*)d_out;
    oF.A[1] = oF.A[2] = nullptr; oF.W[1] = oF.W[2] = nullptr;
    oF.Bi[1] = oF.Bi[2] = nullptr; oF.C[1] = oF.C[2] = nullptr;
    hipLaunchKernelGGL(gemm_f, dim3(8, 20, 1), dim3(256), 0, stream, oF, 512);
}